// Round 9
// baseline (170.462 us; speedup 1.0000x reference)
//
#include <hip/hip_runtime.h>
#include <hip/hip_cooperative_groups.h>
#include <math.h>

namespace cg = cooperative_groups;

#define BB 16
#define CC 256
#define HH 64
#define WW 32
#define NN (HH*WW)            // 2048
#define NEGC (-9e15f)

// scratch as module-scope device globals (capture-safe); every buffer is fully
// rewritten each call before any read -> deterministic across replays.
__device__ float g_wlo[BB*CC];            // channel-softmax weight on c-1
__device__ float g_whi[BB*CC];            // channel-softmax weight on c+1
__device__ float g_Wt[CC*64];             // BN-folded transposed weights: Wt[c][k], k<32 alpha, k>=32 sigma
__device__ float g_bias[64];              // BN-folded bias
__device__ float g_as[(size_t)BB*NN*64];  // as[b][p][k]: alpha (0..31), sigma (32..63)
__device__ float g_part[BB*32*256];       // per-(b,ptile) pair-dot partials over 64 positions
__device__ float g_w8[(size_t)BB*NN*8];   // spatial softmax weights per position

#define WBLK (BB*NN/32)   // 1024 spatial-weight units (32 positions x 8 neighbors each)

// =================== phase bodies as __device__ helpers ===================

__device__ __forceinline__ void prep_unit(int u, int t,
        const float* __restrict__ wa, const float* __restrict__ ga,
        const float* __restrict__ ba, const float* __restrict__ ma,
        const float* __restrict__ va, const float* __restrict__ wsig,
        const float* __restrict__ gs, const float* __restrict__ bs,
        const float* __restrict__ ms, const float* __restrict__ vs) {
    int c = u*16 + (t >> 4);
    int kq = (t & 15) * 4;
    #pragma unroll
    for (int j = 0; j < 4; ++j) {
        int k = kq + j;
        float inv, w;
        if (k < 32) { inv = ga[k] * rsqrtf(va[k] + 1e-5f); w = wa[k*CC + c]; }
        else { int kk = k - 32; inv = gs[kk] * rsqrtf(vs[kk] + 1e-5f); w = wsig[kk*CC + c]; }
        g_Wt[c*64 + k] = w * inv;
    }
    if (u == 0 && t < 64) {
        float inv, bb, mm;
        if (t < 32) { inv = ga[t] * rsqrtf(va[t] + 1e-5f); bb = ba[t]; mm = ma[t]; }
        else { int kk = t - 32; inv = gs[kk] * rsqrtf(vs[kk] + 1e-5f); bb = bs[kk]; mm = ms[kk]; }
        g_bias[t] = bb - mm * inv;
    }
}

// gemm unit: needs smem = 16384 floats (x dbuf 8192 + w dbuf 8192)
__device__ __forceinline__ void gemm_unit(int u, int t, float* smem,
                                          const float* __restrict__ x) {
    float* x_lds = smem;           // [2][64*64]
    float* w_lds = smem + 8192;    // [2][64*64]
    int b = u >> 5;
    int tile = u & 31;
    const float* xb = x + (size_t)b*CC*NN + tile*64;

    #pragma unroll
    for (int i = 0; i < 4; ++i) {
        int idx = t + i*256;             // quad index (1024 quads = 64c x 16q)
        int c = idx >> 4, quad = idx & 15;
        float4 v = *(const float4*)(xb + (size_t)c*NN + quad*4);
        *(float4*)(&x_lds[c*64 + quad*4]) = v;
        float4 w = *(const float4*)(g_Wt + idx*4);
        *(float4*)(&w_lds[idx*4]) = w;
    }
    __syncthreads();    // also orders against the previous unit's buf1 reads

    int kg = t & 15;
    int q  = t >> 4;
    float acc[4][4];
    #pragma unroll
    for (int i = 0; i < 4; ++i)
        #pragma unroll
        for (int j = 0; j < 4; ++j) acc[i][j] = 0.f;

    #pragma unroll
    for (int ct = 0; ct < 4; ++ct) {
        int cur = ct & 1;
        float4 sx[4], sw[4];
        if (ct < 3) {                    // issue next tile's global loads early
            #pragma unroll
            for (int i = 0; i < 4; ++i) {
                int idx = t + i*256;
                int c = idx >> 4, quad = idx & 15;
                sx[i] = *(const float4*)(xb + (size_t)((ct+1)*64 + c)*NN + quad*4);
                sw[i] = *(const float4*)(g_Wt + (ct+1)*64*64 + idx*4);
            }
        }
        const float* xcur = &x_lds[cur*4096];
        const float* wcur = &w_lds[cur*4096];
        #pragma unroll 8
        for (int c = 0; c < 64; ++c) {
            float4 xv = *(const float4*)(xcur + c*64 + q*4);
            float4 wv = *(const float4*)(wcur + c*64 + kg*4);
            acc[0][0] = fmaf(xv.x, wv.x, acc[0][0]);
            acc[0][1] = fmaf(xv.x, wv.y, acc[0][1]);
            acc[0][2] = fmaf(xv.x, wv.z, acc[0][2]);
            acc[0][3] = fmaf(xv.x, wv.w, acc[0][3]);
            acc[1][0] = fmaf(xv.y, wv.x, acc[1][0]);
            acc[1][1] = fmaf(xv.y, wv.y, acc[1][1]);
            acc[1][2] = fmaf(xv.y, wv.z, acc[1][2]);
            acc[1][3] = fmaf(xv.y, wv.w, acc[1][3]);
            acc[2][0] = fmaf(xv.z, wv.x, acc[2][0]);
            acc[2][1] = fmaf(xv.z, wv.y, acc[2][1]);
            acc[2][2] = fmaf(xv.z, wv.z, acc[2][2]);
            acc[2][3] = fmaf(xv.z, wv.w, acc[2][3]);
            acc[3][0] = fmaf(xv.w, wv.x, acc[3][0]);
            acc[3][1] = fmaf(xv.w, wv.y, acc[3][1]);
            acc[3][2] = fmaf(xv.w, wv.z, acc[3][2]);
            acc[3][3] = fmaf(xv.w, wv.w, acc[3][3]);
        }

        // pair-dot partials for pairs c = ct*64 + r (reads current buffer only)
        {
            int r = t >> 2, qg = t & 3;
            int c = ct*64 + r;
            float pp = 0.f;
            if (c < CC-1) {
                const float* rowA = xcur + r*64;
                if (r < 63) {
                    const float* rowB = xcur + (r+1)*64;
                    #pragma unroll
                    for (int j = 0; j < 4; ++j) {
                        int quad = ((qg + r) & 3) + 4*j;   // stagger: 8 bank-quads
                        float4 a  = *(const float4*)(rowA + quad*4);
                        float4 bv = *(const float4*)(rowB + quad*4);
                        pp = fmaf(a.x, bv.x, pp); pp = fmaf(a.y, bv.y, pp);
                        pp = fmaf(a.z, bv.z, pp); pp = fmaf(a.w, bv.w, pp);
                    }
                } else {                 // boundary pair: next tile's first row (L2-hot)
                    const float* rowBg = xb + (size_t)(ct*64 + 64)*NN;
                    #pragma unroll
                    for (int j = 0; j < 4; ++j) {
                        int quad = ((qg + r) & 3) + 4*j;
                        float4 a  = *(const float4*)(rowA + quad*4);
                        float4 bv = *(const float4*)(rowBg + quad*4);
                        pp = fmaf(a.x, bv.x, pp); pp = fmaf(a.y, bv.y, pp);
                        pp = fmaf(a.z, bv.z, pp); pp = fmaf(a.w, bv.w, pp);
                    }
                }
            }
            pp += __shfl_xor(pp, 1, 64);
            pp += __shfl_xor(pp, 2, 64);
            if (qg == 0) g_part[(b*32 + tile)*256 + c] = pp;   // c==255 -> 0
        }

        if (ct < 3) {                    // write staged regs to the other buffer
            int nxt = cur ^ 1;
            #pragma unroll
            for (int i = 0; i < 4; ++i) {
                int idx = t + i*256;
                int c = idx >> 4, quad = idx & 15;
                *(float4*)(&x_lds[nxt*4096 + c*64 + quad*4]) = sx[i];
                *(float4*)(&w_lds[nxt*4096 + idx*4]) = sw[i];
            }
            __syncthreads();
        }
    }

    int kb = kg*4;
    float4 bias = *(const float4*)(g_bias + kb);
    int p0 = tile*64 + q*4;
    float* o = g_as + (((size_t)b*NN + p0) << 6) + kb;
    #pragma unroll
    for (int pi = 0; pi < 4; ++pi) {
        float4 r;
        r.x = fmaxf(acc[pi][0] + bias.x, 0.f);
        r.y = fmaxf(acc[pi][1] + bias.y, 0.f);
        r.z = fmaxf(acc[pi][2] + bias.z, 0.f);
        r.w = fmaxf(acc[pi][3] + bias.w, 0.f);
        *(float4*)(o + (pi << 6)) = r;
    }
}

__device__ __forceinline__ void wc_unit(int u, int t, float* smem) {
    if (u < WBLK) {
        int pos_local = t >> 3, j = t & 7;
        int idx = u*32 + pos_local;
        int b = idx >> 11, p = idx & (NN-1);
        int gr = p >> 5, col = p & 31;
        const int dy[8] = {-1,-1,-1, 0,0, 1,1,1};
        const int dx[8] = {-1, 0, 1,-1,1,-1,0,1};
        int qr = gr + dy[j], qc = col + dx[j];
        bool ok = (qr >= 0) && (qr < HH) && (qc >= 0) && (qc < WW);
        int q = ok ? (qr*WW + qc) : p;
        const float4* ap = (const float4*)(g_as + (((size_t)b*NN + p) << 6));
        const float4* sp = (const float4*)(g_as + (((size_t)b*NN + q) << 6) + 32);
        float d = 0.f;
        #pragma unroll
        for (int k4 = 0; k4 < 8; ++k4) {
            float4 a = ap[k4], s = sp[k4];
            d = fmaf(a.x, s.x, d); d = fmaf(a.y, s.y, d);
            d = fmaf(a.z, s.z, d); d = fmaf(a.w, s.w, d);
        }
        float logit = ok ? d : NEGC;
        float m = logit;                       // max over the 8-lane neighbor group
        m = fmaxf(m, __shfl_xor(m, 1, 64));
        m = fmaxf(m, __shfl_xor(m, 2, 64));
        m = fmaxf(m, __shfl_xor(m, 4, 64));
        float e = expf(logit - m);
        float s8 = e;
        s8 += __shfl_xor(s8, 1, 64);
        s8 += __shfl_xor(s8, 2, 64);
        s8 += __shfl_xor(s8, 4, 64);
        g_w8[(size_t)idx*8 + j] = e / s8;
    } else {
        int b = u - WBLK;
        float s = 0.f;
        #pragma unroll 8
        for (int tile = 0; tile < 32; ++tile) s += g_part[(b*32 + tile)*256 + t];
        __syncthreads();
        smem[t] = s;                           // pair-dot for pair (t, t+1)
        __syncthreads();
        int c = t;
        float glo = (c > 0)      ? smem[c-1] : NEGC;
        float ghi = (c < CC - 1) ? smem[c]   : NEGC;
        float m = fmaxf(glo, ghi);
        float elo = expf(glo - m), ehi = expf(ghi - m);
        float inv = 1.0f / (elo + ehi);
        g_wlo[b*CC + c] = elo * inv;
        g_whi[b*CC + c] = ehi * inv;
        __syncthreads();
    }
}

// main unit: needs smem = 2304 (wtab) + 6480 (xt) floats
__device__ __forceinline__ void main_unit(int u, int t, float* smem, float gama,
                                          const float* __restrict__ x,
                                          float* __restrict__ out) {
    float* wtab = smem;               // [256][9]
    float* xt   = smem + 2304;        // [18*10*36]
    int b = u >> 7;
    int strip = (u >> 4) & 7;
    int cg2 = u & 15;
    int r0 = strip << 3;
    int c0 = cg2 << 4;
    const float* xb = x + (size_t)b*CC*NN;

    {   // stage softmax weights (one thread per position)
        const float4* wsrc = (const float4*)(g_w8 + ((size_t)(b*NN + r0*WW + t))*8);
        float4 w0 = wsrc[0], w1 = wsrc[1];
        wtab[t*9+0]=w0.x; wtab[t*9+1]=w0.y; wtab[t*9+2]=w0.z; wtab[t*9+3]=w0.w;
        wtab[t*9+4]=w1.x; wtab[t*9+5]=w1.y; wtab[t*9+6]=w1.z; wtab[t*9+7]=w1.w;
    }
    // stage x halo tile: 18*10 = 180 row-segments x 8 quads = 1440 float4
    for (int i = t; i < 1440; i += 256) {
        int seg = i >> 3, quad = i & 7;
        int ch_s = seg / 10, r_s = seg - ch_s*10;
        int gc = c0 - 1 + ch_s;  gc = (gc < 0) ? 0 : (gc > CC-1 ? CC-1 : gc);
        int gr = r0 - 1 + r_s;   gr = (gr < 0) ? 0 : (gr > HH-1 ? HH-1 : gr);
        float4 v = *(const float4*)(xb + (size_t)gc*NN + gr*WW + quad*4);
        *(float4*)(&xt[(ch_s*10 + r_s)*36 + quad*4]) = v;
    }
    __syncthreads();

    int wave = __builtin_amdgcn_readfirstlane(t >> 6);
    int lane = t & 63;
    int lrow = lane >> 3;            // row within strip
    int lcq  = (lane & 7) << 2;      // column quad start
    float wq[4][8];
    #pragma unroll
    for (int i = 0; i < 4; ++i) {
        int prow = lrow*32 + lcq + i;
        #pragma unroll
        for (int j = 0; j < 8; ++j) wq[i][j] = wtab[prow*9 + j];
    }
    int cw0 = wave*4;                // this wave's first channel (slot cw0+1)
    int pbase = r0*WW + lane*4;      // for the global store
    float* ob = out + (size_t)b*CC*NN;

    float pm1[4], o0[4];
    {
        float4 v = *(const float4*)(&xt[((cw0+0)*10 + (lrow+1))*36 + lcq]);
        pm1[0]=v.x; pm1[1]=v.y; pm1[2]=v.z; pm1[3]=v.w;
        float4 w = *(const float4*)(&xt[((cw0+1)*10 + (lrow+1))*36 + lcq]);
        o0[0]=w.x; o0[1]=w.y; o0[2]=w.z; o0[3]=w.w;
    }
    #pragma unroll
    for (int cc = 0; cc < 4; ++cc) {
        int c = c0 + cw0 + cc;
        int slot = cw0 + 1 + cc;
        float4 v1 = *(const float4*)(&xt[((slot+1)*10 + (lrow+1))*36 + lcq]);
        float p1[4] = {v1.x, v1.y, v1.z, v1.w};
        float4 va4 = *(const float4*)(&xt[(slot*10 + lrow    )*36 + lcq]);
        float aw[4] = {va4.x, va4.y, va4.z, va4.w};
        float4 vb4 = *(const float4*)(&xt[(slot*10 + lrow + 2)*36 + lcq]);
        float bw[4] = {vb4.x, vb4.y, vb4.z, vb4.w};
        float al  = __shfl_up(aw[3], 1);
        float ar  = __shfl_down(aw[0], 1);
        float ol  = __shfl_up(o0[3], 1);
        float orr = __shfl_down(o0[0], 1);
        float bl  = __shfl_up(bw[3], 1);
        float br  = __shfl_down(bw[0], 1);
        float wlo_c = g_wlo[b*CC + c];
        float whi_c = g_whi[b*CC + c];
        float res[4];
        #pragma unroll
        for (int i = 0; i < 4; ++i) {
            float ul = (i == 0) ? al  : aw[i-1];
            float uu = aw[i];
            float ur = (i == 3) ? ar  : aw[i+1];
            float ll = (i == 0) ? ol  : o0[i-1];
            float rr = (i == 3) ? orr : o0[i+1];
            float dl = (i == 0) ? bl  : bw[i-1];
            float dd = bw[i];
            float dr = (i == 3) ? br  : bw[i+1];
            float hs = wq[i][0]*ul + wq[i][1]*uu + wq[i][2]*ur
                     + wq[i][3]*ll + wq[i][4]*rr
                     + wq[i][5]*dl + wq[i][6]*dd + wq[i][7]*dr;
            float hp = wlo_c*pm1[i] + whi_c*p1[i];
            float h  = hs + hp;
            float el = (h > 0.f) ? h : expm1f(h);
            res[i] = o0[i] + gama*(el - o0[i]);       // (1-g)x + g*h'
        }
        *(float4*)(ob + (size_t)c*NN + pbase) = make_float4(res[0], res[1], res[2], res[3]);
        #pragma unroll
        for (int i = 0; i < 4; ++i) { pm1[i] = o0[i]; o0[i] = p1[i]; }
    }
    __syncthreads();    // LDS reuse guard before next unit's staging
}

// =================== cooperative all-in-one kernel ===================
__global__ __launch_bounds__(256, 2) void k_all(
        const float* __restrict__ x,
        const float* __restrict__ wa, const float* __restrict__ ga,
        const float* __restrict__ ba, const float* __restrict__ ma,
        const float* __restrict__ va, const float* __restrict__ wsig,
        const float* __restrict__ gs, const float* __restrict__ bs,
        const float* __restrict__ ms, const float* __restrict__ vs,
        const float* __restrict__ gama_p, float* __restrict__ out) {
    __shared__ float smem[16384];   // 64 KB, aliased per phase
    cg::grid_group grid = cg::this_grid();
    int blk = blockIdx.x;
    int gdim = gridDim.x;
    int t = threadIdx.x;

    for (int u = blk; u < 16; u += gdim)
        prep_unit(u, t, wa, ga, ba, ma, va, wsig, gs, bs, ms, vs);
    grid.sync();

    for (int u = blk; u < 512; u += gdim)
        gemm_unit(u, t, smem, x);
    grid.sync();

    for (int u = blk; u < WBLK + BB; u += gdim)
        wc_unit(u, t, smem);
    grid.sync();

    float gama = gama_p[0];
    for (int u = blk; u < 2048; u += gdim)
        main_unit(u, t, smem, gama, x, out);
}

// =================== fallback standalone kernels (round-7, verified) ===============
__global__ __launch_bounds__(256) void k_prep(
        const float* __restrict__ wa, const float* __restrict__ ga,
        const float* __restrict__ ba, const float* __restrict__ ma,
        const float* __restrict__ va, const float* __restrict__ wsig,
        const float* __restrict__ gs, const float* __restrict__ bs,
        const float* __restrict__ ms, const float* __restrict__ vs) {
    prep_unit(blockIdx.x, threadIdx.x, wa, ga, ba, ma, va, wsig, gs, bs, ms, vs);
}

__global__ __launch_bounds__(256) void k_gemm(const float* __restrict__ x) {
    __shared__ float smem[16384];
    gemm_unit(blockIdx.x, threadIdx.x, smem, x);
}

__global__ __launch_bounds__(256) void k_wc() {
    __shared__ float smem[256];
    wc_unit(blockIdx.x, threadIdx.x, smem);
}

__global__ __launch_bounds__(256) void k_main(const float* __restrict__ x,
                                              const float* __restrict__ gama_p,
                                              float* __restrict__ out) {
    __shared__ float smem[8784];
    main_unit(blockIdx.x, threadIdx.x, smem, gama_p[0], x, out);
}

extern "C" void kernel_launch(void* const* d_in, const int* in_sizes, int n_in,
                              void* d_out, int out_size, void* d_ws, size_t ws_size,
                              hipStream_t stream) {
    const float* x    = (const float*)d_in[0];
    const float* wa   = (const float*)d_in[1];
    const float* ga   = (const float*)d_in[2];
    const float* ba   = (const float*)d_in[3];
    const float* ma   = (const float*)d_in[4];
    const float* va   = (const float*)d_in[5];
    const float* wsig = (const float*)d_in[6];
    const float* gs   = (const float*)d_in[7];
    const float* bs   = (const float*)d_in[8];
    const float* ms   = (const float*)d_in[9];
    const float* vs   = (const float*)d_in[10];
    const float* gama = (const float*)d_in[11];
    float* out = (float*)d_out;

    void* args[13] = {
        (void*)&x, (void*)&wa, (void*)&ga, (void*)&ba, (void*)&ma, (void*)&va,
        (void*)&wsig, (void*)&gs, (void*)&bs, (void*)&ms, (void*)&vs,
        (void*)&gama, (void*)&out
    };

    bool done = false;
    int dev = 0;
    if (hipGetDevice(&dev) == hipSuccess) {
        int coop = 0;
        hipDeviceGetAttribute(&coop, hipDeviceAttributeCooperativeLaunch, dev);
        if (coop) {
            int maxBlk = 0;
            if (hipOccupancyMaxActiveBlocksPerMultiprocessor(&maxBlk, (const void*)k_all,
                                                             256, 0) != hipSuccess)
                maxBlk = 0;
            if (maxBlk >= 1) {
                int nblk = (maxBlk >= 2) ? 512 : 256;
                if (hipLaunchCooperativeKernel((const void*)k_all, dim3(nblk), dim3(256),
                                               args, 0, stream) == hipSuccess)
                    done = true;
            }
        }
    }
    if (!done) {   // verified round-7 sequence
        hipLaunchKernelGGL(k_prep, dim3(16),       dim3(256), 0, stream,
                           wa, ga, ba, ma, va, wsig, gs, bs, ms, vs);
        hipLaunchKernelGGL(k_gemm, dim3(512),      dim3(256), 0, stream, x);
        hipLaunchKernelGGL(k_wc,   dim3(WBLK+BB),  dim3(256), 0, stream);
        hipLaunchKernelGGL(k_main, dim3(2048),     dim3(256), 0, stream, x, gama, out);
    }
}

// Round 10
// 58.620 us; speedup vs baseline: 2.9079x; 2.9079x over previous
//
#include <hip/hip_runtime.h>
#include <math.h>

#define BB 16
#define CC 256
#define HH 64
#define WW 32
#define NN (HH*WW)            // 2048
#define NEGC (-9e15f)

// scratch (capture-safe device globals; fully rewritten before any read each call)
__device__ float g_as[(size_t)BB*NN*64];  // as[b][p][k]: alpha (0..31), sigma (32..63)
__device__ float g_part[BB*32*256];       // per-(b,ptile) pair-dot partials

// ============ K1: alpha/sigma GEMM (BN fold on load) + pair dots ============
// as[b][p][k] = relu(bias[k] + sum_c W[k][c]*inv[k] * x[b][c][p])
// g_part[b][ptile][c] = sum over ptile's 64 positions of x[b,c,p]*x[b,c+1,p]
// grid 512 = b(16) x ptile(32).  c-tiled (4x64) double-buffered LDS pipeline.
__global__ __launch_bounds__(256) void k_gemm(
        const float* __restrict__ x,
        const float* __restrict__ wa, const float* __restrict__ ga,
        const float* __restrict__ va, const float* __restrict__ ba,
        const float* __restrict__ ma, const float* __restrict__ wsig,
        const float* __restrict__ gs, const float* __restrict__ vs,
        const float* __restrict__ bs, const float* __restrict__ ms) {
    __shared__ float x_lds[2][64*64];   // [buf][c*64 + pos]
    __shared__ float w_lds[2][64*68];   // [buf][c*68 + k]  (pad 68 vs 64)
    int blk = blockIdx.x;
    int b = blk >> 5, tile = blk & 31;
    int t = threadIdx.x;
    const float* xb = x + (size_t)b*CC*NN + tile*64;

    // per-thread W staging info: row k_i = (t>>4) + 16*i
    float inv_i[4];
    const float* wrow_i[4];
    #pragma unroll
    for (int i = 0; i < 4; ++i) {
        int k = (t>>4) + 16*i;
        float g_, v_;
        if (k < 32) { g_ = ga[k]; v_ = va[k]; wrow_i[i] = wa + k*CC; }
        else        { g_ = gs[k-32]; v_ = vs[k-32]; wrow_i[i] = wsig + (k-32)*CC; }
        inv_i[i] = g_ * rsqrtf(v_ + 1e-5f);
    }
    int kg = t & 15;          // k-quad group for FMA / c-quad base for w staging
    int cq4 = kg * 4;

    // stage tile 0 into buf 0
    #pragma unroll
    for (int i = 0; i < 4; ++i) {
        int idx = t + i*256;
        int c = idx >> 4, quad = idx & 15;
        *(float4*)(&x_lds[0][c*64 + quad*4]) =
            *(const float4*)(xb + (size_t)c*NN + quad*4);
        int k = (t>>4) + 16*i;
        float4 wv = *(const float4*)(wrow_i[i] + cq4);       // cols cq4..cq4+3 of tile 0
        wv.x *= inv_i[i]; wv.y *= inv_i[i]; wv.z *= inv_i[i]; wv.w *= inv_i[i];
        w_lds[0][(cq4+0)*68 + k] = wv.x;
        w_lds[0][(cq4+1)*68 + k] = wv.y;
        w_lds[0][(cq4+2)*68 + k] = wv.z;
        w_lds[0][(cq4+3)*68 + k] = wv.w;
    }
    __syncthreads();

    int q = t >> 4;
    float acc[4][4];
    #pragma unroll
    for (int i = 0; i < 4; ++i)
        #pragma unroll
        for (int j = 0; j < 4; ++j) acc[i][j] = 0.f;

    #pragma unroll
    for (int ct = 0; ct < 4; ++ct) {
        int cur = ct & 1;
        float4 sx[4], sw[4];
        if (ct < 3) {                    // issue next tile's global loads early
            #pragma unroll
            for (int i = 0; i < 4; ++i) {
                int idx = t + i*256;
                int c = idx >> 4, quad = idx & 15;
                sx[i] = *(const float4*)(xb + (size_t)((ct+1)*64 + c)*NN + quad*4);
                sw[i] = *(const float4*)(wrow_i[i] + (ct+1)*64 + cq4);
            }
        }
        const float* xcur = &x_lds[cur][0];
        const float* wcur = &w_lds[cur][0];
        #pragma unroll 8
        for (int c = 0; c < 64; ++c) {
            float4 xv = *(const float4*)(xcur + c*64 + q*4);
            float4 wv = *(const float4*)(wcur + c*68 + cq4);
            acc[0][0] = fmaf(xv.x, wv.x, acc[0][0]);
            acc[0][1] = fmaf(xv.x, wv.y, acc[0][1]);
            acc[0][2] = fmaf(xv.x, wv.z, acc[0][2]);
            acc[0][3] = fmaf(xv.x, wv.w, acc[0][3]);
            acc[1][0] = fmaf(xv.y, wv.x, acc[1][0]);
            acc[1][1] = fmaf(xv.y, wv.y, acc[1][1]);
            acc[1][2] = fmaf(xv.y, wv.z, acc[1][2]);
            acc[1][3] = fmaf(xv.y, wv.w, acc[1][3]);
            acc[2][0] = fmaf(xv.z, wv.x, acc[2][0]);
            acc[2][1] = fmaf(xv.z, wv.y, acc[2][1]);
            acc[2][2] = fmaf(xv.z, wv.z, acc[2][2]);
            acc[2][3] = fmaf(xv.z, wv.w, acc[2][3]);
            acc[3][0] = fmaf(xv.w, wv.x, acc[3][0]);
            acc[3][1] = fmaf(xv.w, wv.y, acc[3][1]);
            acc[3][2] = fmaf(xv.w, wv.z, acc[3][2]);
            acc[3][3] = fmaf(xv.w, wv.w, acc[3][3]);
        }

        // pair-dot partials for pairs c = ct*64 + r (reads current x buffer only)
        {
            int r = t >> 2, qg = t & 3;
            int c = ct*64 + r;
            float pp = 0.f;
            if (c < CC-1) {
                const float* rowA = xcur + r*64;
                if (r < 63) {
                    const float* rowB = xcur + (r+1)*64;
                    #pragma unroll
                    for (int j = 0; j < 4; ++j) {
                        int quad = ((qg + r) & 3) + 4*j;
                        float4 a  = *(const float4*)(rowA + quad*4);
                        float4 bv = *(const float4*)(rowB + quad*4);
                        pp = fmaf(a.x, bv.x, pp); pp = fmaf(a.y, bv.y, pp);
                        pp = fmaf(a.z, bv.z, pp); pp = fmaf(a.w, bv.w, pp);
                    }
                } else {                 // boundary pair: next tile's first row (L2-hot)
                    const float* rowBg = xb + (size_t)(ct*64 + 64)*NN;
                    #pragma unroll
                    for (int j = 0; j < 4; ++j) {
                        int quad = ((qg + r) & 3) + 4*j;
                        float4 a  = *(const float4*)(rowA + quad*4);
                        float4 bv = *(const float4*)(rowBg + quad*4);
                        pp = fmaf(a.x, bv.x, pp); pp = fmaf(a.y, bv.y, pp);
                        pp = fmaf(a.z, bv.z, pp); pp = fmaf(a.w, bv.w, pp);
                    }
                }
            }
            pp += __shfl_xor(pp, 1, 64);
            pp += __shfl_xor(pp, 2, 64);
            if (qg == 0) g_part[(b*32 + tile)*256 + c] = pp;   // c==255 -> 0
        }

        if (ct < 3) {                    // write staged regs to the other buffer
            int nxt = cur ^ 1;
            #pragma unroll
            for (int i = 0; i < 4; ++i) {
                int idx = t + i*256;
                int c = idx >> 4, quad = idx & 15;
                *(float4*)(&x_lds[nxt][c*64 + quad*4]) = sx[i];
                float4 wv = sw[i];
                float iv = inv_i[i];
                int k = (t>>4) + 16*i;
                w_lds[nxt][(cq4+0)*68 + k] = wv.x * iv;
                w_lds[nxt][(cq4+1)*68 + k] = wv.y * iv;
                w_lds[nxt][(cq4+2)*68 + k] = wv.z * iv;
                w_lds[nxt][(cq4+3)*68 + k] = wv.w * iv;
            }
            __syncthreads();
        }
    }

    // epilogue: bias for k = cq4..cq4+3, computed from params (L2-hot)
    float4 gv, vv, bv, mv;
    if (cq4 < 32) {
        gv = *(const float4*)(ga + cq4); vv = *(const float4*)(va + cq4);
        bv = *(const float4*)(ba + cq4); mv = *(const float4*)(ma + cq4);
    } else {
        gv = *(const float4*)(gs + cq4-32); vv = *(const float4*)(vs + cq4-32);
        bv = *(const float4*)(bs + cq4-32); mv = *(const float4*)(ms + cq4-32);
    }
    float4 inv4;
    inv4.x = gv.x * rsqrtf(vv.x + 1e-5f);
    inv4.y = gv.y * rsqrtf(vv.y + 1e-5f);
    inv4.z = gv.z * rsqrtf(vv.z + 1e-5f);
    inv4.w = gv.w * rsqrtf(vv.w + 1e-5f);
    float4 bias;
    bias.x = bv.x - mv.x * inv4.x;
    bias.y = bv.y - mv.y * inv4.y;
    bias.z = bv.z - mv.z * inv4.z;
    bias.w = bv.w - mv.w * inv4.w;

    int p0 = tile*64 + q*4;
    float* o = g_as + (((size_t)b*NN + p0) << 6) + cq4;
    #pragma unroll
    for (int pi = 0; pi < 4; ++pi) {
        float4 r;
        r.x = fmaxf(acc[pi][0] + bias.x, 0.f);
        r.y = fmaxf(acc[pi][1] + bias.y, 0.f);
        r.z = fmaxf(acc[pi][2] + bias.z, 0.f);
        r.w = fmaxf(acc[pi][3] + bias.w, 0.f);
        *(float4*)(o + (pi << 6)) = r;
    }
}

// ============ K2: softmaxes (channel + spatial, in-block) + stencil + mix ============
// grid 512 = b(16) x strip(16, 4 rows) x chalf(2).  256 threads.
// smem: wtab 1152 | wlo 256 | whi 256 | tile 13056 (asT [6][32][68] / xt [34][6][36])
#define SM_WT   0
#define SM_WLO  1152
#define SM_WHI  1408
#define SM_T    1664
__global__ __launch_bounds__(256) void k_main(const float* __restrict__ x,
                                              const float* __restrict__ gama_p,
                                              float* __restrict__ out) {
    __shared__ float sm[SM_T + 6*32*68];   // 14720 floats = 58.9 KB
    int blk = blockIdx.x;
    int b = blk >> 5, st = (blk >> 1) & 15, chalf = blk & 1;
    int r0 = st * 4;
    int t = threadIdx.x;

    // 0a: stage as-tile for rows r0-1..r0+4 (clamped), [row][col][68]
    for (int i = t; i < 3072; i += 256) {
        int seg = i >> 4, quad = i & 15;
        int row = seg >> 5, col = seg & 31;
        int gr = r0 - 1 + row; gr = gr < 0 ? 0 : (gr > HH-1 ? HH-1 : gr);
        *(float4*)&sm[SM_T + seg*68 + quad*4] =
            *(const float4*)(g_as + (((size_t)b*NN + gr*WW + col) << 6) + quad*4);
    }
    // 0b: channel pair-dot sums (t = c)
    {
        float s = 0.f;
        #pragma unroll 8
        for (int tl = 0; tl < 32; ++tl) s += g_part[(b*32 + tl)*256 + t];
        sm[SM_WT + t] = s;
    }
    __syncthreads();
    // 0c: channel pair softmax
    {
        float glo = (t > 0)    ? sm[SM_WT + t - 1] : NEGC;
        float ghi = (t < CC-1) ? sm[SM_WT + t]     : NEGC;
        float m = fmaxf(glo, ghi);
        float elo = expf(glo - m), ehi = expf(ghi - m);
        float iv = 1.0f / (elo + ehi);
        __syncthreads();           // pair-sum reads done before wtab is overwritten
        sm[SM_WLO + t] = elo * iv;
        sm[SM_WHI + t] = ehi * iv;
    }
    // 1: spatial softmax weights for the strip's 128 positions
    {
        const int dy[8] = {-1,-1,-1, 0,0, 1,1,1};
        const int dx[8] = {-1, 0, 1,-1,1,-1,0,1};
        int j = t & 7;
        #pragma unroll
        for (int it = 0; it < 4; ++it) {
            int pl = it*32 + (t >> 3);
            int prow = pl >> 5, pcol = pl & 31;
            int qr = r0 + prow + dy[j], qc = pcol + dx[j];
            bool ok = (qr >= 0) && (qr < HH) && (qc >= 0) && (qc < WW);
            int qrt = ok ? (prow + 1 + dy[j]) : (prow + 1);
            int qct = ok ? qc : pcol;
            const float* ap = &sm[SM_T + ((prow+1)*32 + pcol)*68];
            const float* sp = &sm[SM_T + (qrt*32 + qct)*68 + 32];
            float d = 0.f;
            #pragma unroll
            for (int k4 = 0; k4 < 8; ++k4) {
                float4 a  = *(const float4*)(ap + k4*4);
                float4 s4 = *(const float4*)(sp + k4*4);
                d = fmaf(a.x, s4.x, d); d = fmaf(a.y, s4.y, d);
                d = fmaf(a.z, s4.z, d); d = fmaf(a.w, s4.w, d);
            }
            float logit = ok ? d : NEGC;
            float m = logit;
            m = fmaxf(m, __shfl_xor(m, 1, 64));
            m = fmaxf(m, __shfl_xor(m, 2, 64));
            m = fmaxf(m, __shfl_xor(m, 4, 64));
            float e = expf(logit - m);
            float s8 = e;
            s8 += __shfl_xor(s8, 1, 64);
            s8 += __shfl_xor(s8, 2, 64);
            s8 += __shfl_xor(s8, 4, 64);
            sm[SM_WT + pl*9 + j] = e / s8;
        }
    }
    __syncthreads();

    // 2: stencil over 4 chunks of 32 channels
    float gama = gama_p[0];
    int wv_ = t >> 6, lane = t & 63, half = lane >> 5, l5 = lane & 31;
    int lrow = l5 >> 3, cq = l5 & 7, lcq = cq*4;
    float wq[4][8];
    #pragma unroll
    for (int ii = 0; ii < 4; ++ii) {
        int pl = lrow*32 + lcq + ii;
        #pragma unroll
        for (int j = 0; j < 8; ++j) wq[ii][j] = sm[SM_WT + pl*9 + j];
    }

    for (int chunk = 0; chunk < 4; ++chunk) {
        __syncthreads();               // previous chunk's xt reads (or phase-1 asT reads) done
        int cc0 = chalf*128 + chunk*32;
        for (int i = t; i < 1632; i += 256) {
            int seg = i >> 3, quad = i & 7;
            int ch_s = seg / 6, r_s = seg - ch_s*6;
            int gc = cc0 - 1 + ch_s; gc = gc < 0 ? 0 : (gc > CC-1 ? CC-1 : gc);
            int gr = r0 - 1 + r_s;   gr = gr < 0 ? 0 : (gr > HH-1 ? HH-1 : gr);
            *(float4*)&sm[SM_T + seg*36 + quad*4] =
                *(const float4*)(x + ((size_t)b*CC + gc)*NN + gr*WW + quad*4);
        }
        __syncthreads();

        const float* xt = &sm[SM_T];
        int s0  = wv_*8 + half*4 + 1;      // first channel's tile slot
        int ch0 = cc0 + wv_*8 + half*4;    // first global channel
        float pm1[4], o0[4];
        {
            float4 v  = *(const float4*)(xt + ((s0-1)*6 + lrow+1)*36 + lcq);
            pm1[0]=v.x; pm1[1]=v.y; pm1[2]=v.z; pm1[3]=v.w;
            float4 w4 = *(const float4*)(xt + ( s0   *6 + lrow+1)*36 + lcq);
            o0[0]=w4.x; o0[1]=w4.y; o0[2]=w4.z; o0[3]=w4.w;
        }
        #pragma unroll
        for (int cc = 0; cc < 4; ++cc) {
            int slot = s0 + cc, ch = ch0 + cc;
            float4 v1  = *(const float4*)(xt + ((slot+1)*6 + lrow+1)*36 + lcq);
            float p1[4] = {v1.x, v1.y, v1.z, v1.w};
            float4 va4 = *(const float4*)(xt + (slot*6 + lrow    )*36 + lcq);
            float aw[4] = {va4.x, va4.y, va4.z, va4.w};
            float4 vb4 = *(const float4*)(xt + (slot*6 + lrow + 2)*36 + lcq);
            float bw[4] = {vb4.x, vb4.y, vb4.z, vb4.w};
            float al  = __shfl_up(aw[3], 1);
            float ar  = __shfl_down(aw[0], 1);
            float ol  = __shfl_up(o0[3], 1);
            float orr = __shfl_down(o0[0], 1);
            float bl  = __shfl_up(bw[3], 1);
            float br  = __shfl_down(bw[0], 1);
            float wlo_c = sm[SM_WLO + ch];
            float whi_c = sm[SM_WHI + ch];
            float res[4];
            #pragma unroll
            for (int i = 0; i < 4; ++i) {
                float ul = (i == 0) ? al  : aw[i-1];
                float uu = aw[i];
                float ur = (i == 3) ? ar  : aw[i+1];
                float ll = (i == 0) ? ol  : o0[i-1];
                float rr = (i == 3) ? orr : o0[i+1];
                float dl = (i == 0) ? bl  : bw[i-1];
                float dd = bw[i];
                float dr = (i == 3) ? br  : bw[i+1];
                float hs = wq[i][0]*ul + wq[i][1]*uu + wq[i][2]*ur
                         + wq[i][3]*ll + wq[i][4]*rr
                         + wq[i][5]*dl + wq[i][6]*dd + wq[i][7]*dr;
                float hp = wlo_c*pm1[i] + whi_c*p1[i];
                float h  = hs + hp;
                float el = (h > 0.f) ? h : expm1f(h);
                res[i] = o0[i] + gama*(el - o0[i]);       // (1-g)x + g*h'
            }
            *(float4*)(out + ((size_t)b*CC + ch)*NN + (r0+lrow)*WW + lcq) =
                make_float4(res[0], res[1], res[2], res[3]);
            #pragma unroll
            for (int i = 0; i < 4; ++i) { pm1[i] = o0[i]; o0[i] = p1[i]; }
        }
    }
}

extern "C" void kernel_launch(void* const* d_in, const int* in_sizes, int n_in,
                              void* d_out, int out_size, void* d_ws, size_t ws_size,
                              hipStream_t stream) {
    const float* x    = (const float*)d_in[0];
    const float* wa   = (const float*)d_in[1];
    const float* ga   = (const float*)d_in[2];
    const float* ba   = (const float*)d_in[3];
    const float* ma   = (const float*)d_in[4];
    const float* va   = (const float*)d_in[5];
    const float* wsig = (const float*)d_in[6];
    const float* gs   = (const float*)d_in[7];
    const float* bs   = (const float*)d_in[8];
    const float* ms   = (const float*)d_in[9];
    const float* vs   = (const float*)d_in[10];
    const float* gama = (const float*)d_in[11];
    float* out = (float*)d_out;

    hipLaunchKernelGGL(k_gemm, dim3(512), dim3(256), 0, stream,
                       x, wa, ga, va, ba, ma, wsig, gs, vs, bs, ms);
    hipLaunchKernelGGL(k_main, dim3(512), dim3(256), 0, stream, x, gama, out);
}

// Round 11
// 54.681 us; speedup vs baseline: 3.1174x; 1.0720x over previous
//
#include <hip/hip_runtime.h>
#include <math.h>

#define BB 16
#define CC 256
#define HH 64
#define WW 32
#define NN (HH*WW)            // 2048
#define NEGC (-9e15f)

// scratch (capture-safe device globals; fully rewritten before any read each call)
__device__ float g_wlo[BB*CC];            // channel-softmax weight on c-1
__device__ float g_whi[BB*CC];            // channel-softmax weight on c+1
__device__ float g_as[(size_t)BB*NN*64];  // as[b][p][k]: alpha (0..31), sigma (32..63)
__device__ float g_part[BB*32*256];       // per-(b,ptile) pair-dot partials
__device__ float g_w8[(size_t)BB*NN*8];   // spatial softmax weights per position

// ============ K1: alpha/sigma GEMM (BN fold on load) + pair dots ============
// as[b][p][k] = relu(bias[k] + sum_c W[k][c]*inv[k] * x[b][c][p])
// g_part[b][ptile][c] = sum over ptile's 64 positions of x[b,c,p]*x[b,c+1,p]
// grid 512 = b(16) x ptile(32).  c-tiled (4x64) double-buffered LDS pipeline.
__global__ __launch_bounds__(256) void k_gemm(
        const float* __restrict__ x,
        const float* __restrict__ wa, const float* __restrict__ ga,
        const float* __restrict__ va, const float* __restrict__ ba,
        const float* __restrict__ ma, const float* __restrict__ wsig,
        const float* __restrict__ gs, const float* __restrict__ vs,
        const float* __restrict__ bs, const float* __restrict__ ms) {
    __shared__ float x_lds[2][64*64];   // [buf][c*64 + pos]
    __shared__ float w_lds[2][64*68];   // [buf][c*68 + k]  (pad 68 vs 64)
    int blk = blockIdx.x;
    int b = blk >> 5, tile = blk & 31;
    int t = threadIdx.x;
    const float* xb = x + (size_t)b*CC*NN + tile*64;

    // per-thread W staging info: row k_i = (t>>4) + 16*i
    float inv_i[4];
    const float* wrow_i[4];
    #pragma unroll
    for (int i = 0; i < 4; ++i) {
        int k = (t>>4) + 16*i;
        float g_, v_;
        if (k < 32) { g_ = ga[k]; v_ = va[k]; wrow_i[i] = wa + k*CC; }
        else        { g_ = gs[k-32]; v_ = vs[k-32]; wrow_i[i] = wsig + (k-32)*CC; }
        inv_i[i] = g_ * rsqrtf(v_ + 1e-5f);
    }
    int kg = t & 15;          // k-quad group for FMA / c-quad base for w staging
    int cq4 = kg * 4;

    // stage tile 0 into buf 0
    #pragma unroll
    for (int i = 0; i < 4; ++i) {
        int idx = t + i*256;
        int c = idx >> 4, quad = idx & 15;
        *(float4*)(&x_lds[0][c*64 + quad*4]) =
            *(const float4*)(xb + (size_t)c*NN + quad*4);
        int k = (t>>4) + 16*i;
        float4 wv = *(const float4*)(wrow_i[i] + cq4);       // cols cq4..cq4+3 of tile 0
        wv.x *= inv_i[i]; wv.y *= inv_i[i]; wv.z *= inv_i[i]; wv.w *= inv_i[i];
        w_lds[0][(cq4+0)*68 + k] = wv.x;
        w_lds[0][(cq4+1)*68 + k] = wv.y;
        w_lds[0][(cq4+2)*68 + k] = wv.z;
        w_lds[0][(cq4+3)*68 + k] = wv.w;
    }
    __syncthreads();

    int q = t >> 4;
    float acc[4][4];
    #pragma unroll
    for (int i = 0; i < 4; ++i)
        #pragma unroll
        for (int j = 0; j < 4; ++j) acc[i][j] = 0.f;

    #pragma unroll
    for (int ct = 0; ct < 4; ++ct) {
        int cur = ct & 1;
        float4 sx[4], sw[4];
        if (ct < 3) {                    // issue next tile's global loads early
            #pragma unroll
            for (int i = 0; i < 4; ++i) {
                int idx = t + i*256;
                int c = idx >> 4, quad = idx & 15;
                sx[i] = *(const float4*)(xb + (size_t)((ct+1)*64 + c)*NN + quad*4);
                sw[i] = *(const float4*)(wrow_i[i] + (ct+1)*64 + cq4);
            }
        }
        const float* xcur = &x_lds[cur][0];
        const float* wcur = &w_lds[cur][0];
        #pragma unroll 8
        for (int c = 0; c < 64; ++c) {
            float4 xv = *(const float4*)(xcur + c*64 + q*4);
            float4 wv = *(const float4*)(wcur + c*68 + cq4);
            acc[0][0] = fmaf(xv.x, wv.x, acc[0][0]);
            acc[0][1] = fmaf(xv.x, wv.y, acc[0][1]);
            acc[0][2] = fmaf(xv.x, wv.z, acc[0][2]);
            acc[0][3] = fmaf(xv.x, wv.w, acc[0][3]);
            acc[1][0] = fmaf(xv.y, wv.x, acc[1][0]);
            acc[1][1] = fmaf(xv.y, wv.y, acc[1][1]);
            acc[1][2] = fmaf(xv.y, wv.z, acc[1][2]);
            acc[1][3] = fmaf(xv.y, wv.w, acc[1][3]);
            acc[2][0] = fmaf(xv.z, wv.x, acc[2][0]);
            acc[2][1] = fmaf(xv.z, wv.y, acc[2][1]);
            acc[2][2] = fmaf(xv.z, wv.z, acc[2][2]);
            acc[2][3] = fmaf(xv.z, wv.w, acc[2][3]);
            acc[3][0] = fmaf(xv.w, wv.x, acc[3][0]);
            acc[3][1] = fmaf(xv.w, wv.y, acc[3][1]);
            acc[3][2] = fmaf(xv.w, wv.z, acc[3][2]);
            acc[3][3] = fmaf(xv.w, wv.w, acc[3][3]);
        }

        // pair-dot partials for pairs c = ct*64 + r (reads current x buffer only)
        {
            int r = t >> 2, qg = t & 3;
            int c = ct*64 + r;
            float pp = 0.f;
            if (c < CC-1) {
                const float* rowA = xcur + r*64;
                if (r < 63) {
                    const float* rowB = xcur + (r+1)*64;
                    #pragma unroll
                    for (int j = 0; j < 4; ++j) {
                        int quad = ((qg + r) & 3) + 4*j;
                        float4 a  = *(const float4*)(rowA + quad*4);
                        float4 bv = *(const float4*)(rowB + quad*4);
                        pp = fmaf(a.x, bv.x, pp); pp = fmaf(a.y, bv.y, pp);
                        pp = fmaf(a.z, bv.z, pp); pp = fmaf(a.w, bv.w, pp);
                    }
                } else {                 // boundary pair: next tile's first row (L2-hot)
                    const float* rowBg = xb + (size_t)(ct*64 + 64)*NN;
                    #pragma unroll
                    for (int j = 0; j < 4; ++j) {
                        int quad = ((qg + r) & 3) + 4*j;
                        float4 a  = *(const float4*)(rowA + quad*4);
                        float4 bv = *(const float4*)(rowBg + quad*4);
                        pp = fmaf(a.x, bv.x, pp); pp = fmaf(a.y, bv.y, pp);
                        pp = fmaf(a.z, bv.z, pp); pp = fmaf(a.w, bv.w, pp);
                    }
                }
            }
            pp += __shfl_xor(pp, 1, 64);
            pp += __shfl_xor(pp, 2, 64);
            if (qg == 0) g_part[(b*32 + tile)*256 + c] = pp;   // c==255 -> 0
        }

        if (ct < 3) {                    // write staged regs to the other buffer
            int nxt = cur ^ 1;
            #pragma unroll
            for (int i = 0; i < 4; ++i) {
                int idx = t + i*256;
                int c = idx >> 4, quad = idx & 15;
                *(float4*)(&x_lds[nxt][c*64 + quad*4]) = sx[i];
                float4 wv = sw[i];
                float iv = inv_i[i];
                int k = (t>>4) + 16*i;
                w_lds[nxt][(cq4+0)*68 + k] = wv.x * iv;
                w_lds[nxt][(cq4+1)*68 + k] = wv.y * iv;
                w_lds[nxt][(cq4+2)*68 + k] = wv.z * iv;
                w_lds[nxt][(cq4+3)*68 + k] = wv.w * iv;
            }
            __syncthreads();
        }
    }

    // epilogue: bias for k = cq4..cq4+3, computed from params (L2-hot)
    float4 gv, vv, bv, mv;
    if (cq4 < 32) {
        gv = *(const float4*)(ga + cq4); vv = *(const float4*)(va + cq4);
        bv = *(const float4*)(ba + cq4); mv = *(const float4*)(ma + cq4);
    } else {
        gv = *(const float4*)(gs + cq4-32); vv = *(const float4*)(vs + cq4-32);
        bv = *(const float4*)(bs + cq4-32); mv = *(const float4*)(ms + cq4-32);
    }
    float4 inv4;
    inv4.x = gv.x * rsqrtf(vv.x + 1e-5f);
    inv4.y = gv.y * rsqrtf(vv.y + 1e-5f);
    inv4.z = gv.z * rsqrtf(vv.z + 1e-5f);
    inv4.w = gv.w * rsqrtf(vv.w + 1e-5f);
    float4 bias;
    bias.x = bv.x - mv.x * inv4.x;
    bias.y = bv.y - mv.y * inv4.y;
    bias.z = bv.z - mv.z * inv4.z;
    bias.w = bv.w - mv.w * inv4.w;

    int p0 = tile*64 + q*4;
    float* o = g_as + (((size_t)b*NN + p0) << 6) + cq4;
    #pragma unroll
    for (int pi = 0; pi < 4; ++pi) {
        float4 r;
        r.x = fmaxf(acc[pi][0] + bias.x, 0.f);
        r.y = fmaxf(acc[pi][1] + bias.y, 0.f);
        r.z = fmaxf(acc[pi][2] + bias.z, 0.f);
        r.w = fmaxf(acc[pi][3] + bias.w, 0.f);
        *(float4*)(o + (pi << 6)) = r;
    }
}

// ---------------- K2: spatial softmax weights (blocks < WBLK) + channel softmax (rest) ----
#define WBLK (BB*NN/32)   // 1024: each block does 32 positions x 8 neighbors
__global__ __launch_bounds__(256) void k_wc() {
    __shared__ float lds_s[256];
    int blk = blockIdx.x;
    int t = threadIdx.x;
    if (blk < WBLK) {
        int pos_local = t >> 3, j = t & 7;
        int idx = blk*32 + pos_local;
        int b = idx >> 11, p = idx & (NN-1);
        int gr = p >> 5, col = p & 31;
        const int dy[8] = {-1,-1,-1, 0,0, 1,1,1};
        const int dx[8] = {-1, 0, 1,-1,1,-1,0,1};
        int qr = gr + dy[j], qc = col + dx[j];
        bool ok = (qr >= 0) && (qr < HH) && (qc >= 0) && (qc < WW);
        int q = ok ? (qr*WW + qc) : p;
        const float4* ap = (const float4*)(g_as + (((size_t)b*NN + p) << 6));
        const float4* sp = (const float4*)(g_as + (((size_t)b*NN + q) << 6) + 32);
        float d = 0.f;
        #pragma unroll
        for (int k4 = 0; k4 < 8; ++k4) {
            float4 a = ap[k4], s = sp[k4];
            d = fmaf(a.x, s.x, d); d = fmaf(a.y, s.y, d);
            d = fmaf(a.z, s.z, d); d = fmaf(a.w, s.w, d);
        }
        float logit = ok ? d : NEGC;
        float m = logit;                       // max over the 8-lane neighbor group
        m = fmaxf(m, __shfl_xor(m, 1, 64));
        m = fmaxf(m, __shfl_xor(m, 2, 64));
        m = fmaxf(m, __shfl_xor(m, 4, 64));
        float e = expf(logit - m);
        float s8 = e;
        s8 += __shfl_xor(s8, 1, 64);
        s8 += __shfl_xor(s8, 2, 64);
        s8 += __shfl_xor(s8, 4, 64);
        g_w8[(size_t)idx*8 + j] = e / s8;
    } else {
        int b = blk - WBLK;
        float s = 0.f;
        #pragma unroll 8
        for (int tile = 0; tile < 32; ++tile) s += g_part[(b*32 + tile)*256 + t];
        lds_s[t] = s;                          // pair-dot for pair (t, t+1)
        __syncthreads();
        int c = t;
        float glo = (c > 0)      ? lds_s[c-1] : NEGC;
        float ghi = (c < CC - 1) ? lds_s[c]   : NEGC;
        float m = fmaxf(glo, ghi);
        float elo = expf(glo - m), ehi = expf(ghi - m);
        float inv = 1.0f / (elo + ehi);
        g_wlo[b*CC + c] = elo * inv;
        g_whi[b*CC + c] = ehi * inv;
    }
}

// ---------------- K3: stencil + channel blend + elu + mix (LDS-staged halo tile) ----
// grid: 2048 blocks = b(16) x strip(8 rows)(8) x cgroup(16 ch)(16); 4 waves = 4 ch each
__global__ __launch_bounds__(256) void k_main(const float* __restrict__ x,
                                              const float* __restrict__ gama_p,
                                              float* __restrict__ out) {
    __shared__ float wtab[256][9];
    __shared__ float xt[18*10*36];
    int blk = blockIdx.x;
    int b = blk >> 7;
    int strip = (blk >> 4) & 7;
    int cg = blk & 15;
    int t = threadIdx.x;
    int r0 = strip << 3;
    int c0 = cg << 4;
    const float* xb = x + (size_t)b*CC*NN;

    {   // stage softmax weights (one thread per position)
        const float4* wsrc = (const float4*)(g_w8 + ((size_t)(b*NN + r0*WW + t))*8);
        float4 w0 = wsrc[0], w1 = wsrc[1];
        wtab[t][0]=w0.x; wtab[t][1]=w0.y; wtab[t][2]=w0.z; wtab[t][3]=w0.w;
        wtab[t][4]=w1.x; wtab[t][5]=w1.y; wtab[t][6]=w1.z; wtab[t][7]=w1.w;
    }
    // stage x halo tile: 18*10 = 180 row-segments x 8 quads = 1440 float4
    for (int i = t; i < 1440; i += 256) {
        int seg = i >> 3, quad = i & 7;
        int ch_s = seg / 10, r_s = seg - ch_s*10;
        int gc = c0 - 1 + ch_s;  gc = (gc < 0) ? 0 : (gc > CC-1 ? CC-1 : gc);
        int gr = r0 - 1 + r_s;   gr = (gr < 0) ? 0 : (gr > HH-1 ? HH-1 : gr);
        float4 v = *(const float4*)(xb + (size_t)gc*NN + gr*WW + quad*4);
        *(float4*)(&xt[(ch_s*10 + r_s)*36 + quad*4]) = v;
    }
    __syncthreads();

    int wave = __builtin_amdgcn_readfirstlane(t >> 6);
    int lane = t & 63;
    int lrow = lane >> 3;            // row within strip
    int lcq  = (lane & 7) << 2;      // column quad start
    float wq[4][8];
    #pragma unroll
    for (int i = 0; i < 4; ++i) {
        int prow = lrow*32 + lcq + i;
        #pragma unroll
        for (int j = 0; j < 8; ++j) wq[i][j] = wtab[prow][j];
    }
    float gama = gama_p[0];
    int cw0 = wave*4;                // this wave's first channel (slot cw0+1)
    int pbase = r0*WW + lane*4;      // for the global store
    float* ob = out + (size_t)b*CC*NN;

    float pm1[4], o0[4];
    {
        float4 v = *(const float4*)(&xt[((cw0+0)*10 + (lrow+1))*36 + lcq]);   // slot c0-1+cw0
        pm1[0]=v.x; pm1[1]=v.y; pm1[2]=v.z; pm1[3]=v.w;
        float4 w = *(const float4*)(&xt[((cw0+1)*10 + (lrow+1))*36 + lcq]);   // own channel
        o0[0]=w.x; o0[1]=w.y; o0[2]=w.z; o0[3]=w.w;
    }
    #pragma unroll
    for (int cc = 0; cc < 4; ++cc) {
        int c = c0 + cw0 + cc;
        int slot = cw0 + 1 + cc;
        float4 v1 = *(const float4*)(&xt[((slot+1)*10 + (lrow+1))*36 + lcq]); // c+1 (clamped)
        float p1[4] = {v1.x, v1.y, v1.z, v1.w};
        float4 va4 = *(const float4*)(&xt[(slot*10 + lrow    )*36 + lcq]);    // row above (clamped)
        float aw[4] = {va4.x, va4.y, va4.z, va4.w};
        float4 vb4 = *(const float4*)(&xt[(slot*10 + lrow + 2)*36 + lcq]);    // row below (clamped)
        float bw[4] = {vb4.x, vb4.y, vb4.z, vb4.w};
        float al  = __shfl_up(aw[3], 1);
        float ar  = __shfl_down(aw[0], 1);
        float ol  = __shfl_up(o0[3], 1);
        float orr = __shfl_down(o0[0], 1);
        float bl  = __shfl_up(bw[3], 1);
        float br  = __shfl_down(bw[0], 1);
        float wlo_c = g_wlo[b*CC + c];
        float whi_c = g_whi[b*CC + c];
        float res[4];
        #pragma unroll
        for (int i = 0; i < 4; ++i) {
            float ul = (i == 0) ? al  : aw[i-1];
            float uu = aw[i];
            float ur = (i == 3) ? ar  : aw[i+1];
            float ll = (i == 0) ? ol  : o0[i-1];
            float rr = (i == 3) ? orr : o0[i+1];
            float dl = (i == 0) ? bl  : bw[i-1];
            float dd = bw[i];
            float dr = (i == 3) ? br  : bw[i+1];
            float hs = wq[i][0]*ul + wq[i][1]*uu + wq[i][2]*ur
                     + wq[i][3]*ll + wq[i][4]*rr
                     + wq[i][5]*dl + wq[i][6]*dd + wq[i][7]*dr;
            float hp = wlo_c*pm1[i] + whi_c*p1[i];
            float h  = hs + hp;
            float el = (h > 0.f) ? h : expm1f(h);
            res[i] = o0[i] + gama*(el - o0[i]);       // (1-g)x + g*h'
        }
        *(float4*)(ob + (size_t)c*NN + pbase) = make_float4(res[0], res[1], res[2], res[3]);
        #pragma unroll
        for (int i = 0; i < 4; ++i) { pm1[i] = o0[i]; o0[i] = p1[i]; }
    }
}

extern "C" void kernel_launch(void* const* d_in, const int* in_sizes, int n_in,
                              void* d_out, int out_size, void* d_ws, size_t ws_size,
                              hipStream_t stream) {
    const float* x    = (const float*)d_in[0];
    const float* wa   = (const float*)d_in[1];
    const float* ga   = (const float*)d_in[2];
    const float* ba   = (const float*)d_in[3];
    const float* ma   = (const float*)d_in[4];
    const float* va   = (const float*)d_in[5];
    const float* wsig = (const float*)d_in[6];
    const float* gs   = (const float*)d_in[7];
    const float* bs   = (const float*)d_in[8];
    const float* ms   = (const float*)d_in[9];
    const float* vs   = (const float*)d_in[10];
    const float* gama = (const float*)d_in[11];
    float* out = (float*)d_out;

    hipLaunchKernelGGL(k_gemm, dim3(512),      dim3(256), 0, stream,
                       x, wa, ga, va, ba, ma, wsig, gs, vs, bs, ms);
    hipLaunchKernelGGL(k_wc,   dim3(WBLK+BB),  dim3(256), 0, stream);
    hipLaunchKernelGGL(k_main, dim3(2048),     dim3(256), 0, stream, x, gama, out);
}

// Round 12
// 47.546 us; speedup vs baseline: 3.5852x; 1.1501x over previous
//
#include <hip/hip_runtime.h>
#include <math.h>

#define BB 16
#define CC 256
#define HH 64
#define WW 32
#define NN (HH*WW)            // 2048
#define NEGC (-9e15f)
#define CPAD 136              // bf16 elems per LDS row: 272B stride, 16B-aligned rows

typedef __attribute__((ext_vector_type(8))) short bf16x8;
typedef __attribute__((ext_vector_type(4))) float f32x4;

// scratch (capture-safe device globals; fully rewritten before any read each call)
__device__ float g_wlo[BB*CC];            // channel-softmax weight on c-1
__device__ float g_whi[BB*CC];            // channel-softmax weight on c+1
__device__ float g_as[(size_t)BB*NN*64];  // as[b][p][k]: alpha (0..31), sigma (32..63)
__device__ float g_part[BB*32*256];       // per-(b,ptile) pair-dot partials
__device__ float g_w8[(size_t)BB*NN*8];   // spatial softmax weights per position

__device__ __forceinline__ unsigned short f2bf(float f) {   // RNE f32->bf16
    unsigned int u = __float_as_uint(f);
    u += 0x7FFFu + ((u >> 16) & 1u);
    return (unsigned short)(u >> 16);
}

// ============ K1: alpha/sigma GEMM via MFMA bf16 + fp32 pair dots ============
// as[b][p][k] = relu(bias[k] + sum_c (W[k][c]*inv[k]) * x[b][c][p])   (bf16 MFMA)
// g_part[b][ptile][c] = sum over ptile's 64 positions of x*x (fp32, from global regs)
// grid 512 = b(16) x ptile(32).  Two 128-channel halves staged in LDS.
__global__ __launch_bounds__(256) void k_gemm(
        const float* __restrict__ x,
        const float* __restrict__ wa, const float* __restrict__ ga,
        const float* __restrict__ va, const float* __restrict__ ba,
        const float* __restrict__ ma, const float* __restrict__ wsig,
        const float* __restrict__ gs, const float* __restrict__ vs,
        const float* __restrict__ bs, const float* __restrict__ ms) {
    __shared__ unsigned short xbuf[64*CPAD];   // [p][c_local] bf16
    __shared__ unsigned short wbuf[64*CPAD];   // [k][c_local] bf16 (BN-folded)
    int blk = blockIdx.x;
    int b = blk >> 5, tile = blk & 31;
    int t = threadIdx.x;
    int p0 = tile*64;
    const float* xb = x + (size_t)b*CC*NN + p0;

    // W staging row info: thread t stages k = t>>2, 32 c's at sub*32
    int kw = t >> 2, sub = t & 3;
    const float* wrow; float g_, v_;
    if (kw < 32) { g_ = ga[kw]; v_ = va[kw]; wrow = wa + kw*CC; }
    else         { g_ = gs[kw-32]; v_ = vs[kw-32]; wrow = wsig + (kw-32)*CC; }
    float invk = g_ * rsqrtf(v_ + 1e-5f);

    // x staging / pair-dot map: thread = (g = t>>4: 8-c-row group, q = t&15: pos quad)
    int g = t >> 4, q = t & 15;
    int wv_ = t >> 6;                 // wave id: 16 positions per wave
    int lane = t & 63;
    int pcol = lane & 15, grp = lane >> 4;

    f32x4 acc[4];
    #pragma unroll
    for (int i = 0; i < 4; ++i) acc[i] = (f32x4){0.f, 0.f, 0.f, 0.f};

    #pragma unroll
    for (int h = 0; h < 2; ++h) {
        if (h) __syncthreads();       // prior half's MFMA reads complete
        // ---- stage x (bf16 transpose scatter) + fp32 pair partials ----
        float pp[8];
        #pragma unroll
        for (int i = 0; i < 8; ++i) pp[i] = 0.f;
        float4 prev = make_float4(0.f, 0.f, 0.f, 0.f);
        #pragma unroll
        for (int i = 0; i <= 8; ++i) {
            int c = h*128 + g*8 + i;
            float4 v = make_float4(0.f, 0.f, 0.f, 0.f);
            if (c < CC) v = *(const float4*)(xb + (size_t)c*NN + q*4);
            if (i < 8) {
                int cl = g*8 + i;
                xbuf[(q*4+0)*CPAD + cl] = f2bf(v.x);
                xbuf[(q*4+1)*CPAD + cl] = f2bf(v.y);
                xbuf[(q*4+2)*CPAD + cl] = f2bf(v.z);
                xbuf[(q*4+3)*CPAD + cl] = f2bf(v.w);
            }
            if (i > 0) {
                pp[i-1] = fmaf(prev.x, v.x, pp[i-1]);
                pp[i-1] = fmaf(prev.y, v.y, pp[i-1]);
                pp[i-1] = fmaf(prev.z, v.z, pp[i-1]);
                pp[i-1] = fmaf(prev.w, v.w, pp[i-1]);
            }
            prev = v;
        }
        // reduce each pair over the 16 q-lanes (contiguous 16-lane group in-wave)
        float myv = 0.f;
        #pragma unroll
        for (int i = 0; i < 8; ++i) {
            float r = pp[i];
            r += __shfl_xor(r, 1, 64);
            r += __shfl_xor(r, 2, 64);
            r += __shfl_xor(r, 4, 64);
            r += __shfl_xor(r, 8, 64);
            if (q == i) myv = r;
        }
        if (q < 8) {
            int c = h*128 + g*8 + q;          // c==255 -> myv==0 (zero row product)
            g_part[(b*32 + tile)*256 + c] = myv;
        }
        // ---- stage W (BN-folded, bf16) ----
        #pragma unroll
        for (int m = 0; m < 8; ++m) {
            int cl = sub*32 + m*4;
            float4 w4 = *(const float4*)(wrow + h*128 + cl);
            unsigned int pk0 = (unsigned int)f2bf(w4.x*invk) |
                               ((unsigned int)f2bf(w4.y*invk) << 16);
            unsigned int pk1 = (unsigned int)f2bf(w4.z*invk) |
                               ((unsigned int)f2bf(w4.w*invk) << 16);
            *(unsigned int*)&wbuf[kw*CPAD + cl]     = pk0;
            *(unsigned int*)&wbuf[kw*CPAD + cl + 2] = pk1;
        }
        __syncthreads();
        // ---- MFMA: 4 c-steps x 4 k-tiles ----
        #pragma unroll
        for (int cs = 0; cs < 4; ++cs) {
            int c_off = cs*32 + grp*8;
            bf16x8 bfrag = *(const bf16x8*)&xbuf[(wv_*16 + pcol)*CPAD + c_off];
            #pragma unroll
            for (int kt = 0; kt < 4; ++kt) {
                bf16x8 afrag = *(const bf16x8*)&wbuf[(kt*16 + pcol)*CPAD + c_off];
                acc[kt] = __builtin_amdgcn_mfma_f32_16x16x32_bf16(afrag, bfrag, acc[kt], 0, 0, 0);
            }
        }
    }

    // epilogue: D[row=k'=grp*4+reg][col=p'=pcol]; bias recomputed inline
    #pragma unroll
    for (int kt = 0; kt < 4; ++kt) {
        int k0 = kt*16 + grp*4;
        float4 gv, vv, bv, mv;
        if (k0 < 32) {
            gv = *(const float4*)(ga + k0); vv = *(const float4*)(va + k0);
            bv = *(const float4*)(ba + k0); mv = *(const float4*)(ma + k0);
        } else {
            gv = *(const float4*)(gs + k0-32); vv = *(const float4*)(vs + k0-32);
            bv = *(const float4*)(bs + k0-32); mv = *(const float4*)(ms + k0-32);
        }
        float i0 = gv.x * rsqrtf(vv.x + 1e-5f);
        float i1 = gv.y * rsqrtf(vv.y + 1e-5f);
        float i2 = gv.z * rsqrtf(vv.z + 1e-5f);
        float i3 = gv.w * rsqrtf(vv.w + 1e-5f);
        float4 r;
        r.x = fmaxf(acc[kt][0] + (bv.x - mv.x*i0), 0.f);
        r.y = fmaxf(acc[kt][1] + (bv.y - mv.y*i1), 0.f);
        r.z = fmaxf(acc[kt][2] + (bv.z - mv.z*i2), 0.f);
        r.w = fmaxf(acc[kt][3] + (bv.w - mv.w*i3), 0.f);
        *(float4*)(g_as + (((size_t)(b*NN + p0 + wv_*16 + pcol)) << 6) + k0) = r;
    }
}

// ---------------- K2: spatial softmax weights (blocks < WBLK) + channel softmax (rest) ----
#define WBLK (BB*NN/32)   // 1024: each block does 32 positions x 8 neighbors
__global__ __launch_bounds__(256) void k_wc() {
    __shared__ float lds_s[256];
    int blk = blockIdx.x;
    int t = threadIdx.x;
    if (blk < WBLK) {
        int pos_local = t >> 3, j = t & 7;
        int idx = blk*32 + pos_local;
        int b = idx >> 11, p = idx & (NN-1);
        int gr = p >> 5, col = p & 31;
        const int dy[8] = {-1,-1,-1, 0,0, 1,1,1};
        const int dx[8] = {-1, 0, 1,-1,1,-1,0,1};
        int qr = gr + dy[j], qc = col + dx[j];
        bool ok = (qr >= 0) && (qr < HH) && (qc >= 0) && (qc < WW);
        int q = ok ? (qr*WW + qc) : p;
        const float4* ap = (const float4*)(g_as + (((size_t)b*NN + p) << 6));
        const float4* sp = (const float4*)(g_as + (((size_t)b*NN + q) << 6) + 32);
        float d = 0.f;
        #pragma unroll
        for (int k4 = 0; k4 < 8; ++k4) {
            float4 a = ap[k4], s = sp[k4];
            d = fmaf(a.x, s.x, d); d = fmaf(a.y, s.y, d);
            d = fmaf(a.z, s.z, d); d = fmaf(a.w, s.w, d);
        }
        float logit = ok ? d : NEGC;
        float m = logit;                       // max over the 8-lane neighbor group
        m = fmaxf(m, __shfl_xor(m, 1, 64));
        m = fmaxf(m, __shfl_xor(m, 2, 64));
        m = fmaxf(m, __shfl_xor(m, 4, 64));
        float e = expf(logit - m);
        float s8 = e;
        s8 += __shfl_xor(s8, 1, 64);
        s8 += __shfl_xor(s8, 2, 64);
        s8 += __shfl_xor(s8, 4, 64);
        g_w8[(size_t)idx*8 + j] = e / s8;
    } else {
        int b = blk - WBLK;
        float s = 0.f;
        #pragma unroll 8
        for (int tile = 0; tile < 32; ++tile) s += g_part[(b*32 + tile)*256 + t];
        lds_s[t] = s;                          // pair-dot for pair (t, t+1)
        __syncthreads();
        int c = t;
        float glo = (c > 0)      ? lds_s[c-1] : NEGC;
        float ghi = (c < CC - 1) ? lds_s[c]   : NEGC;
        float m = fmaxf(glo, ghi);
        float elo = expf(glo - m), ehi = expf(ghi - m);
        float inv = 1.0f / (elo + ehi);
        g_wlo[b*CC + c] = elo * inv;
        g_whi[b*CC + c] = ehi * inv;
    }
}

// ---------------- K3: stencil + channel blend + elu + mix (LDS-staged halo tile) ----
// grid: 2048 blocks = b(16) x strip(8 rows)(8) x cgroup(16 ch)(16); 4 waves = 4 ch each
__global__ __launch_bounds__(256) void k_main(const float* __restrict__ x,
                                              const float* __restrict__ gama_p,
                                              float* __restrict__ out) {
    __shared__ float wtab[256][9];
    __shared__ float xt[18*10*36];
    int blk = blockIdx.x;
    int b = blk >> 7;
    int strip = (blk >> 4) & 7;
    int cg = blk & 15;
    int t = threadIdx.x;
    int r0 = strip << 3;
    int c0 = cg << 4;
    const float* xb = x + (size_t)b*CC*NN;

    {   // stage softmax weights (one thread per position)
        const float4* wsrc = (const float4*)(g_w8 + ((size_t)(b*NN + r0*WW + t))*8);
        float4 w0 = wsrc[0], w1 = wsrc[1];
        wtab[t][0]=w0.x; wtab[t][1]=w0.y; wtab[t][2]=w0.z; wtab[t][3]=w0.w;
        wtab[t][4]=w1.x; wtab[t][5]=w1.y; wtab[t][6]=w1.z; wtab[t][7]=w1.w;
    }
    // stage x halo tile: 18*10 = 180 row-segments x 8 quads = 1440 float4
    for (int i = t; i < 1440; i += 256) {
        int seg = i >> 3, quad = i & 7;
        int ch_s = seg / 10, r_s = seg - ch_s*10;
        int gc = c0 - 1 + ch_s;  gc = (gc < 0) ? 0 : (gc > CC-1 ? CC-1 : gc);
        int gr = r0 - 1 + r_s;   gr = (gr < 0) ? 0 : (gr > HH-1 ? HH-1 : gr);
        float4 v = *(const float4*)(xb + (size_t)gc*NN + gr*WW + quad*4);
        *(float4*)(&xt[(ch_s*10 + r_s)*36 + quad*4]) = v;
    }
    __syncthreads();

    int wave = __builtin_amdgcn_readfirstlane(t >> 6);
    int lane = t & 63;
    int lrow = lane >> 3;            // row within strip
    int lcq  = (lane & 7) << 2;      // column quad start
    float wq[4][8];
    #pragma unroll
    for (int i = 0; i < 4; ++i) {
        int prow = lrow*32 + lcq + i;
        #pragma unroll
        for (int j = 0; j < 8; ++j) wq[i][j] = wtab[prow][j];
    }
    float gama = gama_p[0];
    int cw0 = wave*4;                // this wave's first channel (slot cw0+1)
    int pbase = r0*WW + lane*4;      // for the global store
    float* ob = out + (size_t)b*CC*NN;

    float pm1[4], o0[4];
    {
        float4 v = *(const float4*)(&xt[((cw0+0)*10 + (lrow+1))*36 + lcq]);   // slot c0-1+cw0
        pm1[0]=v.x; pm1[1]=v.y; pm1[2]=v.z; pm1[3]=v.w;
        float4 w = *(const float4*)(&xt[((cw0+1)*10 + (lrow+1))*36 + lcq]);   // own channel
        o0[0]=w.x; o0[1]=w.y; o0[2]=w.z; o0[3]=w.w;
    }
    #pragma unroll
    for (int cc = 0; cc < 4; ++cc) {
        int c = c0 + cw0 + cc;
        int slot = cw0 + 1 + cc;
        float4 v1 = *(const float4*)(&xt[((slot+1)*10 + (lrow+1))*36 + lcq]); // c+1 (clamped)
        float p1[4] = {v1.x, v1.y, v1.z, v1.w};
        float4 va4 = *(const float4*)(&xt[(slot*10 + lrow    )*36 + lcq]);    // row above (clamped)
        float aw[4] = {va4.x, va4.y, va4.z, va4.w};
        float4 vb4 = *(const float4*)(&xt[(slot*10 + lrow + 2)*36 + lcq]);    // row below (clamped)
        float bw[4] = {vb4.x, vb4.y, vb4.z, vb4.w};
        float al  = __shfl_up(aw[3], 1);
        float ar  = __shfl_down(aw[0], 1);
        float ol  = __shfl_up(o0[3], 1);
        float orr = __shfl_down(o0[0], 1);
        float bl  = __shfl_up(bw[3], 1);
        float br  = __shfl_down(bw[0], 1);
        float wlo_c = g_wlo[b*CC + c];
        float whi_c = g_whi[b*CC + c];
        float res[4];
        #pragma unroll
        for (int i = 0; i < 4; ++i) {
            float ul = (i == 0) ? al  : aw[i-1];
            float uu = aw[i];
            float ur = (i == 3) ? ar  : aw[i+1];
            float ll = (i == 0) ? ol  : o0[i-1];
            float rr = (i == 3) ? orr : o0[i+1];
            float dl = (i == 0) ? bl  : bw[i-1];
            float dd = bw[i];
            float dr = (i == 3) ? br  : bw[i+1];
            float hs = wq[i][0]*ul + wq[i][1]*uu + wq[i][2]*ur
                     + wq[i][3]*ll + wq[i][4]*rr
                     + wq[i][5]*dl + wq[i][6]*dd + wq[i][7]*dr;
            float hp = wlo_c*pm1[i] + whi_c*p1[i];
            float h  = hs + hp;
            float el = (h > 0.f) ? h : expm1f(h);
            res[i] = o0[i] + gama*(el - o0[i]);       // (1-g)x + g*h'
        }
        *(float4*)(ob + (size_t)c*NN + pbase) = make_float4(res[0], res[1], res[2], res[3]);
        #pragma unroll
        for (int i = 0; i < 4; ++i) { pm1[i] = o0[i]; o0[i] = p1[i]; }
    }
}

extern "C" void kernel_launch(void* const* d_in, const int* in_sizes, int n_in,
                              void* d_out, int out_size, void* d_ws, size_t ws_size,
                              hipStream_t stream) {
    const float* x    = (const float*)d_in[0];
    const float* wa   = (const float*)d_in[1];
    const float* ga   = (const float*)d_in[2];
    const float* ba   = (const float*)d_in[3];
    const float* ma   = (const float*)d_in[4];
    const float* va   = (const float*)d_in[5];
    const float* wsig = (const float*)d_in[6];
    const float* gs   = (const float*)d_in[7];
    const float* bs   = (const float*)d_in[8];
    const float* ms   = (const float*)d_in[9];
    const float* vs   = (const float*)d_in[10];
    const float* gama = (const float*)d_in[11];
    float* out = (float*)d_out;

    hipLaunchKernelGGL(k_gemm, dim3(512),      dim3(256), 0, stream,
                       x, wa, ga, va, ba, ma, wsig, gs, vs, bs, ms);
    hipLaunchKernelGGL(k_wc,   dim3(WBLK+BB),  dim3(256), 0, stream);
    hipLaunchKernelGGL(k_main, dim3(2048),     dim3(256), 0, stream, x, gama, out);
}